// Round 2
// baseline (411.503 us; speedup 1.0000x reference)
//
#include <hip/hip_runtime.h>
#include <math.h>

// problem constants
#define CH    128     // TO*DOUT
#define HO    62
#define WO    62
#define XROW  36      // xpatch row stride in floats (34 data + 2 zero pad)
#define NROWS 192     // (ti*8+di)*3+kh rows
#define VSTR  33      // v transpose buffer row stride

// One WG = 256 threads = 4 waves. Each wave owns 8 output pixels of one row.
// WG covers 32 columns (half an output row). Grid = 8 n * 62 ho * 2 halves.
// Lane l: to = l&15, dp = l>>4; owns channels ch0 = to*8+dp, ch1 = ch0+4.
// uhat[ti][ch0/ch1][px] lives entirely in registers (128 VGPRs).
// Routing: softmax over to = shfl_xor over lane bits 0..3;
//          do-reductions  = in-lane pair + shfl_xor over lane bits 4..5.

__global__ __launch_bounds__(256, 2)
void caps_fused(const float* __restrict__ x, const float* __restrict__ w,
                const float* __restrict__ cbias, const float* __restrict__ rbias,
                float* __restrict__ out)
{
    __shared__ alignas(16) float lds[NROWS * XROW];   // 6912 floats = 27.6 KB

    const int tid  = threadIdx.x;
    const int lane = tid & 63;
    const int wave = tid >> 6;
    const int to   = lane & 15;
    const int dp   = lane >> 4;
    const int ch0  = to * 8 + dp;
    const int ch1  = ch0 + 4;

    const int bid  = blockIdx.x;
    const int n    = bid / 124;
    const int rem  = bid - n * 124;
    const int ho   = rem >> 1;
    const int half = rem & 1;
    const int w0c  = half * 32;

    // ---------------- stage x patch (192 rows x 34 cols, zero-padded) --------
    {
        const float* xb = x + (size_t)n * 262144;   // n * 8*8*64*64
        for (int i = tid; i < NROWS * XROW; i += 256) {
            int row  = i / XROW;
            int col  = i - row * XROW;
            int tidi = row / 3;
            int kh   = row - tidi * 3;
            int g    = w0c + col;
            float v  = 0.f;
            if (col < 34 && g < 64)
                v = xb[(size_t)tidi * 4096 + (ho + kh) * 64 + g];
            lds[row * XROW + col] = v;
        }
    }
    __syncthreads();

    // ---------------- grouped conv: uhat into registers ----------------------
    float uh0[8][8], uh1[8][8];
    #pragma unroll
    for (int ti = 0; ti < 8; ++ti)
        #pragma unroll
        for (int p = 0; p < 8; ++p) { uh0[ti][p] = 0.f; uh1[ti][p] = 0.f; }

    #pragma unroll
    for (int ti = 0; ti < 8; ++ti) {
        const float4* wp0 = (const float4*)(w + (size_t)(ti * CH + ch0) * 72);
        const float4* wp1 = (const float4*)(w + (size_t)(ti * CH + ch1) * 72);
        #pragma unroll
        for (int dh = 0; dh < 2; ++dh) {            // di halves: 0..3, 4..7
            float wr0[36], wr1[36];
            #pragma unroll
            for (int q = 0; q < 9; ++q) {
                float4 a = wp0[dh * 9 + q];
                wr0[q*4+0] = a.x; wr0[q*4+1] = a.y; wr0[q*4+2] = a.z; wr0[q*4+3] = a.w;
                float4 b = wp1[dh * 9 + q];
                wr1[q*4+0] = b.x; wr1[q*4+1] = b.y; wr1[q*4+2] = b.z; wr1[q*4+3] = b.w;
            }
            #pragma unroll
            for (int dd = 0; dd < 4; ++dd) {
                #pragma unroll
                for (int kh = 0; kh < 3; ++kh) {
                    int row = (ti * 8 + dh * 4 + dd) * 3 + kh;
                    const float4* xr4 = (const float4*)(lds + row * XROW + wave * 8);
                    float xv[12];
                    #pragma unroll
                    for (int q = 0; q < 3; ++q) {
                        float4 t = xr4[q];
                        xv[q*4+0] = t.x; xv[q*4+1] = t.y; xv[q*4+2] = t.z; xv[q*4+3] = t.w;
                    }
                    #pragma unroll
                    for (int kw = 0; kw < 3; ++kw) {
                        float a0 = wr0[dd*9 + kh*3 + kw];
                        float a1 = wr1[dd*9 + kh*3 + kw];
                        #pragma unroll
                        for (int p = 0; p < 8; ++p) {
                            uh0[ti][p] = fmaf(a0, xv[p + kw], uh0[ti][p]);
                            uh1[ti][p] = fmaf(a1, xv[p + kw], uh1[ti][p]);
                        }
                    }
                }
            }
        }
        float cb0 = cbias[ti * CH + ch0];
        float cb1 = cbias[ti * CH + ch1];
        #pragma unroll
        for (int p = 0; p < 8; ++p) { uh0[ti][p] += cb0; uh1[ti][p] += cb1; }
    }

    // ---------------- dynamic routing, all in-wave ---------------------------
    // breg[0][p] = b[ti=dp][to], breg[1][p] = b[ti=dp+4][to]
    float breg[2][8];
    #pragma unroll
    for (int p = 0; p < 8; ++p) { breg[0][p] = 0.f; breg[1][p] = 0.f; }

    const float rb0 = rbias[to * 8 + dp];
    const float rb1 = rbias[to * 8 + dp + 4];
    float v0[8], v1[8];

    #pragma unroll
    for (int r = 0; r < 3; ++r) {
        float s0[8], s1[8];
        #pragma unroll
        for (int p = 0; p < 8; ++p) { s0[p] = rb0; s1[p] = rb1; }

        if (r == 0) {
            // softmax of zeros -> c = 1/16 exactly
            #pragma unroll
            for (int ti = 0; ti < 8; ++ti)
                #pragma unroll
                for (int p = 0; p < 8; ++p) {
                    s0[p] = fmaf(0.0625f, uh0[ti][p], s0[p]);
                    s1[p] = fmaf(0.0625f, uh1[ti][p], s1[p]);
                }
        } else {
            #pragma unroll
            for (int ti = 0; ti < 8; ++ti) {
                const int src = (lane & 15) | ((ti & 3) << 4);
                #pragma unroll
                for (int p = 0; p < 8; ++p) {
                    float bv = __shfl(breg[ti >> 2][p], src);   // b[ti][to]
                    float m = bv;
                    m = fmaxf(m, __shfl_xor(m, 1));
                    m = fmaxf(m, __shfl_xor(m, 2));
                    m = fmaxf(m, __shfl_xor(m, 4));
                    m = fmaxf(m, __shfl_xor(m, 8));
                    float e = __expf(bv - m);
                    float Z = e;
                    Z += __shfl_xor(Z, 1);
                    Z += __shfl_xor(Z, 2);
                    Z += __shfl_xor(Z, 4);
                    Z += __shfl_xor(Z, 8);
                    float c = __fdividef(e, Z);
                    s0[p] = fmaf(c, uh0[ti][p], s0[p]);
                    s1[p] = fmaf(c, uh1[ti][p], s1[p]);
                }
            }
        }

        // squash over do: in-lane pair + dp groups (lane bits 4,5)
        #pragma unroll
        for (int p = 0; p < 8; ++p) {
            float n2 = s0[p] * s0[p] + s1[p] * s1[p];
            n2 += __shfl_xor(n2, 16);
            n2 += __shfl_xor(n2, 32);
            float sc = n2 / (1.f + n2) * rsqrtf(n2 + 1e-9f);
            v0[p] = s0[p] * sc;
            v1[p] = s1[p] * sc;
        }

        if (r < 2) {
            // agreement: b[ti][to] += sum_do uhat*v
            #pragma unroll
            for (int ti = 0; ti < 8; ++ti) {
                const bool mine = (dp == (ti & 3));
                #pragma unroll
                for (int p = 0; p < 8; ++p) {
                    float a = uh0[ti][p] * v0[p] + uh1[ti][p] * v1[p];
                    a += __shfl_xor(a, 16);
                    a += __shfl_xor(a, 32);
                    breg[ti >> 2][p] += mine ? a : 0.f;
                }
            }
        }
    }

    // ---------------- output: LDS transpose then coalesced store -------------
    __syncthreads();          // all xpatch reads finished before aliasing
    float* vbuf = lds;        // 128 x 33 floats
    #pragma unroll
    for (int p = 0; p < 8; ++p) {
        vbuf[ch0 * VSTR + wave * 8 + p] = v0[p];
        vbuf[ch1 * VSTR + wave * 8 + p] = v1[p];
    }
    __syncthreads();

    for (int i = tid; i < CH * 32; i += 256) {
        int c    = i >> 5;
        int pcol = i & 31;
        int wc   = w0c + pcol;
        if (wc < 62)
            out[(size_t)(n * CH + c) * 3844 + ho * 62 + wc] = vbuf[c * VSTR + pcol];
    }
}

extern "C" void kernel_launch(void* const* d_in, const int* in_sizes, int n_in,
                              void* d_out, int out_size, void* d_ws, size_t ws_size,
                              hipStream_t stream) {
    const float* x  = (const float*)d_in[0];
    const float* cw = (const float*)d_in[1];
    const float* cb = (const float*)d_in[2];
    const float* rb = (const float*)d_in[3];
    float* out = (float*)d_out;

    const int n_wg = 8 * HO * 2;   // 992
    caps_fused<<<n_wg, 256, 0, stream>>>(x, cw, cb, rb, out);
}

// Round 3
// 333.885 us; speedup vs baseline: 1.2325x; 1.2325x over previous
//
#include <hip/hip_runtime.h>
#include <math.h>

#define N_      8
#define HO      62
#define WO      62
#define CHN     128          // To*Do
#define XP_STR  20           // xpatch row stride (18 cols + pad)
#define XP_ROWS 192          // (ti*8+di)*3+kh
#define XP_FLOATS (XP_ROWS*XP_STR)      // 3840
#define SQ_OFF  XP_FLOATS               // 512 floats: [g][h][to][px]
#define AG_OFF  (SQ_OFF+512)            // 4096 floats: [g][h][ti][to][px]
#define LDS_TOT (AG_OFF+4096)           // 8448 floats = 33.8 KB
#define WPACK_FLOATS (1024*96)          // repacked weights: [ti*128+ch][4 slots][24]

// ---- one-time weight repack into d_ws: 18-float (ti,ch,di-pair) rows padded
// ---- to 24 floats so the conv can use aligned float4 loads with 20 live regs.
__global__ void repack_w(const float* __restrict__ w, float* __restrict__ wp) {
    int idx = blockIdx.x * 256 + threadIdx.x;
    if (idx >= WPACK_FLOATS) return;
    int row  = idx / 96;            // ti*128+ch
    int r    = idx - row * 96;
    int slot = r / 24;              // dh*2+dp2
    int j    = r - slot * 24;
    float v = 0.f;
    if (j < 18) v = w[row * 72 + slot * 18 + j];
    wp[idx] = v;
}

// One WG = 4 waves. Waves (g,h): g = px-group (8 px), h = do-half.
// Lane: to = lane&15, dhalf = lane>>4; do = h*4+dhalf; ch = to*8+do.
// uh[8 ti][8 px] in registers (64 VGPRs). Softmax over to: shfl bits 0..3.
// do-reductions: shfl bits 4..5 (own half) + LDS exchange across h.
// b[ti][px]: lane owns ti = dhalf*2+{0,1} -> breg[2][8], gathered by shfl.
template<bool PACKED>
__global__ __launch_bounds__(256, 4)
void caps_main(const float* __restrict__ x, const float* __restrict__ wsrc,
               const float* __restrict__ cbias, const float* __restrict__ rbias,
               float* __restrict__ out)
{
    __shared__ float lds[LDS_TOT];
    const int tid   = threadIdx.x;
    const int lane  = tid & 63;
    const int wv    = tid >> 6;
    const int h     = wv & 1;
    const int g     = wv >> 1;
    const int to    = lane & 15;
    const int dhalf = lane >> 4;
    const int doo   = h * 4 + dhalf;
    const int ch    = to * 8 + doo;

    const int bid = blockIdx.x;
    const int n   = bid / 248;
    const int rem = bid - n * 248;
    const int ho  = rem >> 2;
    const int wo0 = (rem & 3) << 4;     // 16-px chunk base

    // ---------------- stage x patch: 192 rows x 18 cols ----------------------
    {
        const float* xb = x + (size_t)n * 262144;
        for (int i = tid; i < XP_ROWS * 18; i += 256) {
            int row  = i / 18;
            int col  = i - row * 18;
            int tidi = row / 3;
            int kh   = row - tidi * 3;
            int gc   = wo0 + col;
            float v  = (gc < 64) ? xb[(size_t)tidi * 4096 + (ho + kh) * 64 + gc] : 0.f;
            lds[row * XP_STR + col] = v;
        }
    }
    __syncthreads();

    // ---------------- grouped conv: uh[ti][px] in registers ------------------
    float uh[8][8];
    #pragma unroll
    for (int t = 0; t < 8; ++t)
        #pragma unroll
        for (int p = 0; p < 8; ++p) uh[t][p] = 0.f;

    const int xcol = g * 8;
    #pragma unroll
    for (int ti = 0; ti < 8; ++ti) {
        #pragma unroll
        for (int dh = 0; dh < 2; ++dh) {
            #pragma unroll
            for (int dp2 = 0; dp2 < 2; ++dp2) {
                float wf[20];
                if (PACKED) {
                    const float4* wp4 = (const float4*)
                        (wsrc + (size_t)(ti * CHN + ch) * 96 + (dh * 2 + dp2) * 24);
                    #pragma unroll
                    for (int q = 0; q < 5; ++q) {
                        float4 t4 = wp4[q];
                        wf[q*4+0] = t4.x; wf[q*4+1] = t4.y;
                        wf[q*4+2] = t4.z; wf[q*4+3] = t4.w;
                    }
                } else {
                    const float* wr = wsrc + (size_t)(ti * CHN + ch) * 72 + dh * 36 + dp2 * 18;
                    #pragma unroll
                    for (int j = 0; j < 18; ++j) wf[j] = wr[j];
                }
                #pragma unroll
                for (int ddl = 0; ddl < 2; ++ddl) {
                    const int di = dh * 4 + dp2 * 2 + ddl;
                    #pragma unroll
                    for (int kh = 0; kh < 3; ++kh) {
                        const float* xr = lds + ((ti * 8 + di) * 3 + kh) * XP_STR + xcol;
                        float xvv[10];
                        {
                            float4 a  = ((const float4*)xr)[0];
                            float4 b4 = ((const float4*)xr)[1];
                            float2 c2 = ((const float2*)xr)[4];
                            xvv[0]=a.x;  xvv[1]=a.y;  xvv[2]=a.z;  xvv[3]=a.w;
                            xvv[4]=b4.x; xvv[5]=b4.y; xvv[6]=b4.z; xvv[7]=b4.w;
                            xvv[8]=c2.x; xvv[9]=c2.y;
                        }
                        #pragma unroll
                        for (int kw = 0; kw < 3; ++kw) {
                            float wvv = wf[ddl * 9 + kh * 3 + kw];
                            #pragma unroll
                            for (int p = 0; p < 8; ++p)
                                uh[ti][p] = fmaf(wvv, xvv[p + kw], uh[ti][p]);
                        }
                    }
                }
            }
        }
        float cbv = cbias[ti * CHN + ch];
        #pragma unroll
        for (int p = 0; p < 8; ++p) uh[ti][p] += cbv;
    }

    // ---------------- dynamic routing ----------------------------------------
    float breg[2][8];                  // b for ti = dhalf*2 + {0,1}
    #pragma unroll
    for (int k = 0; k < 2; ++k)
        #pragma unroll
        for (int p = 0; p < 8; ++p) breg[k][p] = 0.f;

    const float rb = rbias[ch];
    float vvv[8];

    float* sqb = lds + SQ_OFF;
    float* agb = lds + AG_OFF;
    const int gh  = g * 2 + h;
    const int ghX = g * 2 + (h ^ 1);

    #pragma unroll
    for (int r = 0; r < 3; ++r) {
        float s[8];
        #pragma unroll
        for (int p = 0; p < 8; ++p) s[p] = rb;

        if (r == 0) {
            // b==0 -> c = 1/16 exactly
            #pragma unroll
            for (int ti = 0; ti < 8; ++ti)
                #pragma unroll
                for (int p = 0; p < 8; ++p)
                    s[p] = fmaf(0.0625f, uh[ti][p], s[p]);
        } else {
            #pragma unroll
            for (int ti = 0; ti < 8; ++ti) {
                const int src = ((ti >> 1) << 4) | to;
                #pragma unroll
                for (int p = 0; p < 8; ++p) {
                    float bv = __shfl(breg[ti & 1][p], src);   // b[ti][to][px]
                    float m = bv;
                    m = fmaxf(m, __shfl_xor(m, 1));
                    m = fmaxf(m, __shfl_xor(m, 2));
                    m = fmaxf(m, __shfl_xor(m, 4));
                    m = fmaxf(m, __shfl_xor(m, 8));
                    float e = __expf(bv - m);
                    float Z = e;
                    Z += __shfl_xor(Z, 1);
                    Z += __shfl_xor(Z, 2);
                    Z += __shfl_xor(Z, 4);
                    Z += __shfl_xor(Z, 8);
                    float c = __fdividef(e, Z);
                    s[p] = fmaf(c, uh[ti][p], s[p]);
                }
            }
        }

        // squash over do: in-wave (bits 4,5) + cross-half via LDS
        float n2p[8];
        #pragma unroll
        for (int p = 0; p < 8; ++p) {
            float q = s[p] * s[p];
            q += __shfl_xor(q, 16);
            q += __shfl_xor(q, 32);
            n2p[p] = q;
        }
        if (dhalf == 0) {
            #pragma unroll
            for (int p = 0; p < 8; ++p)
                sqb[(gh * 16 + to) * 8 + p] = n2p[p];
        }
        __syncthreads();
        #pragma unroll
        for (int p = 0; p < 8; ++p) {
            float n2 = n2p[p] + sqb[(ghX * 16 + to) * 8 + p];
            float sc = n2 / (1.f + n2) * rsqrtf(n2 + 1e-9f);
            vvv[p] = s[p] * sc;
        }

        if (r < 2) {
            // agreement: a[ti][to][px] = sum_do uh*v ; partials exchanged via LDS
            #pragma unroll
            for (int ti = 0; ti < 8; ++ti) {
                float ap[8];
                #pragma unroll
                for (int p = 0; p < 8; ++p) {
                    float a = uh[ti][p] * vvv[p];
                    a += __shfl_xor(a, 16);
                    a += __shfl_xor(a, 32);
                    ap[p] = a;
                }
                if (dhalf == (ti >> 1)) {      // owners stash their half's partial
                    #pragma unroll
                    for (int p = 0; p < 8; ++p)
                        agb[((gh * 8 + ti) * 16 + to) * 8 + p] = ap[p];
                }
            }
            __syncthreads();
            #pragma unroll
            for (int k = 0; k < 2; ++k) {
                const int tia = dhalf * 2 + k;
                #pragma unroll
                for (int p = 0; p < 8; ++p) {
                    float a0 = agb[(((g * 2 + 0) * 8 + tia) * 16 + to) * 8 + p];
                    float a1 = agb[(((g * 2 + 1) * 8 + tia) * 16 + to) * 8 + p];
                    breg[k][p] += a0 + a1;
                }
            }
        }
    }

    // ---------------- output: LDS transpose then coalesced-ish store ---------
    __syncthreads();                    // all sqb reads done; vbuf aliases xpatch
    float* vbuf = lds;                  // 128 x 17
    #pragma unroll
    for (int p = 0; p < 8; ++p)
        vbuf[ch * 17 + g * 8 + p] = vvv[p];
    __syncthreads();

    {
        int chh = tid >> 1;
        int jb  = (tid & 1) * 8;
        size_t obase = ((size_t)(n * CHN + chh)) * 3844 + ho * 62 + wo0 + jb;
        #pragma unroll
        for (int j = 0; j < 8; ++j) {
            int wc = wo0 + jb + j;
            if (wc < 62) out[obase + j] = vbuf[chh * 17 + jb + j];
        }
    }
}

extern "C" void kernel_launch(void* const* d_in, const int* in_sizes, int n_in,
                              void* d_out, int out_size, void* d_ws, size_t ws_size,
                              hipStream_t stream) {
    const float* x  = (const float*)d_in[0];
    const float* cw = (const float*)d_in[1];
    const float* cb = (const float*)d_in[2];
    const float* rb = (const float*)d_in[3];
    float* out = (float*)d_out;

    const int n_wg = N_ * HO * 4;   // 1984
    if (ws_size >= (size_t)WPACK_FLOATS * sizeof(float)) {
        float* wp = (float*)d_ws;
        repack_w<<<(WPACK_FLOATS + 255) / 256, 256, 0, stream>>>(cw, wp);
        caps_main<true><<<n_wg, 256, 0, stream>>>(x, wp, cb, rb, out);
    } else {
        caps_main<false><<<n_wg, 256, 0, stream>>>(x, cw, cb, rb, out);
    }
}

// Round 4
// 185.948 us; speedup vs baseline: 2.2130x; 1.7956x over previous
//
#include <hip/hip_runtime.h>
#include <math.h>

#define N_      8
#define HO      62
#define WO      62
#define CHN     128                    // To*Do
#define UH_STR  1032                   // halves per px (1024 + 8 pad)
#define UH_F    (16 * UH_STR / 2)      // uhat region in floats: 8256
#define XP_STR  20                     // xpatch row stride (18 data cols)
#define XP_ROWS 192                    // (ti*8+di)*3+kh
#define LDS_F   (UH_F + XP_ROWS * XP_STR)   // 8256 + 3840 = 12096 floats = 48384 B

typedef __attribute__((ext_vector_type(8))) _Float16 half8;

// WG = 256 threads, 16 output px (one 16-col chunk of one row).
// Phase 1 (conv): thread = (ch 0..127, grp 0..1); grp covers px [8g, 8g+8).
//   W[72] in regs per ti (rolled loop), x rows broadcast from LDS, acc[8].
//   uhat -> LDS fp16 [px][ti][to][do].
// Phase 2 (routing): thread = (px 0..15, to 0..15). b[ti] thread-local.
//   softmax over to = shfl_xor lane bits 0..3; squash/agreement in-lane
//   over do via one ds_read_b128 (8 halves) per (ti).
__global__ __launch_bounds__(256, 3)
void caps_main(const float* __restrict__ x, const float* __restrict__ w,
               const float* __restrict__ cbias, const float* __restrict__ rbias,
               float* __restrict__ out)
{
    __shared__ alignas(16) float lds[LDS_F];
    _Float16* uhx = (_Float16*)lds;          // 16 px * 1032 halves
    float*    xp  = lds + UH_F;              // 192 rows * 20 floats

    const int tid = threadIdx.x;

    // XCD-aware bijective swizzle: 1984 = 8 * 248
    const int bid  = blockIdx.x;
    const int work = (bid & 7) * 248 + (bid >> 3);
    const int n    = work / 248;
    const int rem  = work - n * 248;
    const int ho   = rem >> 2;
    const int wo0  = (rem & 3) << 4;

    // ---------------- stage x patch: 192 rows x 18 cols (fp32) ---------------
    {
        const float* xb = x + (size_t)n * 262144;
        for (int i = tid; i < XP_ROWS * 18; i += 256) {
            int row  = i / 18;
            int col  = i - row * 18;
            int tidi = row / 3;
            int kh   = row - tidi * 3;
            int gc   = wo0 + col;
            float v  = (gc < 64) ? xb[(size_t)tidi * 4096 + (ho + kh) * 64 + gc] : 0.f;
            xp[row * XP_STR + col] = v;
        }
    }
    __syncthreads();

    // ---------------- grouped conv -> uhat (fp16) in LDS ---------------------
    {
        const int ch  = tid & 127;
        const int grp = tid >> 7;
        const int pxb = grp * 8;

        for (int ti = 0; ti < 8; ++ti) {       // rolled: one ti's weights live
            float wreg[72];
            {
                const float4* wp = (const float4*)(w + (size_t)(ti * CHN + ch) * 72);
                #pragma unroll
                for (int q = 0; q < 18; ++q) {
                    float4 t4 = wp[q];
                    wreg[4*q+0] = t4.x; wreg[4*q+1] = t4.y;
                    wreg[4*q+2] = t4.z; wreg[4*q+3] = t4.w;
                }
            }
            float acc[8];
            #pragma unroll
            for (int p = 0; p < 8; ++p) acc[p] = 0.f;

            #pragma unroll
            for (int di = 0; di < 8; ++di) {
                #pragma unroll
                for (int kh = 0; kh < 3; ++kh) {
                    const float* xr = xp + ((ti * 8 + di) * 3 + kh) * XP_STR + pxb;
                    float xv[10];
                    {
                        float4 a = ((const float4*)xr)[0];
                        float4 b = ((const float4*)xr)[1];
                        float2 c = ((const float2*)(xr + 8))[0];
                        xv[0]=a.x; xv[1]=a.y; xv[2]=a.z; xv[3]=a.w;
                        xv[4]=b.x; xv[5]=b.y; xv[6]=b.z; xv[7]=b.w;
                        xv[8]=c.x; xv[9]=c.y;
                    }
                    #pragma unroll
                    for (int kw = 0; kw < 3; ++kw) {
                        float wv = wreg[di * 9 + kh * 3 + kw];
                        #pragma unroll
                        for (int p = 0; p < 8; ++p)
                            acc[p] = fmaf(wv, xv[p + kw], acc[p]);
                    }
                }
            }
            float cbv = cbias[ti * CHN + ch];
            #pragma unroll
            for (int p = 0; p < 8; ++p)
                uhx[(size_t)(pxb + p) * UH_STR + ti * 128 + ch] =
                    (_Float16)(acc[p] + cbv);
        }
    }
    __syncthreads();

    // ---------------- dynamic routing: thread = (px, to) ---------------------
    const int px = tid >> 4;
    const int to = tid & 15;
    const _Float16* uhp = uhx + (size_t)px * UH_STR + to * 8;

    float rb[8];
    #pragma unroll
    for (int d = 0; d < 8; ++d) rb[d] = rbias[to * 8 + d];

    float breg[8];
    #pragma unroll
    for (int t = 0; t < 8; ++t) breg[t] = 0.f;

    float v[8];

    for (int r = 0; r < 3; ++r) {
        float s[8];
        #pragma unroll
        for (int d = 0; d < 8; ++d) s[d] = rb[d];

        #pragma unroll
        for (int ti = 0; ti < 8; ++ti) {
            float c;
            if (r == 0) {
                c = 0.0625f;                    // softmax of zeros over 16
            } else {
                float bv = breg[ti];
                float m = bv;
                m = fmaxf(m, __shfl_xor(m, 1));
                m = fmaxf(m, __shfl_xor(m, 2));
                m = fmaxf(m, __shfl_xor(m, 4));
                m = fmaxf(m, __shfl_xor(m, 8));
                float e = __expf(bv - m);
                float Z = e;
                Z += __shfl_xor(Z, 1);
                Z += __shfl_xor(Z, 2);
                Z += __shfl_xor(Z, 4);
                Z += __shfl_xor(Z, 8);
                c = __fdividef(e, Z);
            }
            half8 hv = *(const half8*)(uhp + ti * 128);
            s[0] = fmaf(c, (float)hv[0], s[0]);
            s[1] = fmaf(c, (float)hv[1], s[1]);
            s[2] = fmaf(c, (float)hv[2], s[2]);
            s[3] = fmaf(c, (float)hv[3], s[3]);
            s[4] = fmaf(c, (float)hv[4], s[4]);
            s[5] = fmaf(c, (float)hv[5], s[5]);
            s[6] = fmaf(c, (float)hv[6], s[6]);
            s[7] = fmaf(c, (float)hv[7], s[7]);
        }

        // squash over do: fully in-lane
        float n2 = s[0] * s[0];
        #pragma unroll
        for (int d = 1; d < 8; ++d) n2 = fmaf(s[d], s[d], n2);
        float sc = n2 / (1.f + n2) * rsqrtf(n2 + 1e-9f);
        #pragma unroll
        for (int d = 0; d < 8; ++d) v[d] = s[d] * sc;

        if (r < 2) {
            // agreement: b[ti] += <uh[ti][to][:], v>  (in-lane dot over do)
            #pragma unroll
            for (int ti = 0; ti < 8; ++ti) {
                half8 hv = *(const half8*)(uhp + ti * 128);
                float a =        v[0] * (float)hv[0];
                a = fmaf(v[1], (float)hv[1], a);
                a = fmaf(v[2], (float)hv[2], a);
                a = fmaf(v[3], (float)hv[3], a);
                a = fmaf(v[4], (float)hv[4], a);
                a = fmaf(v[5], (float)hv[5], a);
                a = fmaf(v[6], (float)hv[6], a);
                a = fmaf(v[7], (float)hv[7], a);
                breg[ti] += a;
            }
        }
    }

    // ---------------- output: transpose via LDS (aliases xpatch) -------------
    float* vbuf = xp;                       // [ch][17], 2176 floats < 3840
    #pragma unroll
    for (int d = 0; d < 8; ++d)
        vbuf[(to * 8 + d) * 17 + px] = v[d];
    __syncthreads();

    {
        int chh = tid >> 1;
        int jb  = (tid & 1) * 8;
        int wc0 = wo0 + jb;
        const float* vr = vbuf + chh * 17 + jb;
        size_t ob = ((size_t)(n * CHN + chh)) * 3844 + (size_t)ho * 62 + wc0;
        #pragma unroll
        for (int j = 0; j < 8; ++j)
            if (wc0 + j < 62) out[ob + j] = vr[j];
    }
}

extern "C" void kernel_launch(void* const* d_in, const int* in_sizes, int n_in,
                              void* d_out, int out_size, void* d_ws, size_t ws_size,
                              hipStream_t stream) {
    const float* x  = (const float*)d_in[0];
    const float* cw = (const float*)d_in[1];
    const float* cb = (const float*)d_in[2];
    const float* rb = (const float*)d_in[3];
    float* out = (float*)d_out;

    const int n_wg = N_ * HO * 4;   // 1984 = 8 XCDs * 248
    caps_main<<<n_wg, 256, 0, stream>>>(x, cw, cb, rb, out);
}

// Round 5
// 122.623 us; speedup vs baseline: 3.3558x; 1.5164x over previous
//
#include <hip/hip_runtime.h>
#include <math.h>

#define N_      8
#define HO      62
#define CHN     128
#define UH_STR  1032                       // halves per px (1024 + 8 pad)
#define XP_STR  20                         // xpatch row stride (18 data cols)
#define XP_ROWS 192
// LDS float offsets:
//   xf  (B-fragments): 1536 tuples * 8 halves = 6144 floats  @ 0
//   xp  (fp32 x patch): 3840 floats                          @ 6144  (ends 9984)
//   uhx (f16 uhat, aliases xf+xp after conv): 8256 floats    @ 0
//   vbuf (output transpose): 2176 floats                     @ 8256  (ends 10432)
#define XP_OFF  6144
#define VB_OFF  8256
#define LDS_F   10432

typedef _Float16 half8  __attribute__((ext_vector_type(8)));
typedef _Float16 half4v __attribute__((ext_vector_type(4)));
typedef float    f32x4  __attribute__((ext_vector_type(4)));

#define W_TUPLES 12288                     // 8 ti * 8 mt * 3 ks * 64 lanes
#define WPACK_BYTES (W_TUPLES * 16)        // 196608

// ---- one-time weight repack: fp32 w -> f16 A-fragments in d_ws -------------
// tuple t = ((ti*8+mt)*3+ks)*64 + lane ; elem j: W[ti][mt*16+(lane&15)][k]
// with k = ks*32 + (lane>>4)*8 + j, zero-padded past K=72.
__global__ void repack_w(const float* __restrict__ w, _Float16* __restrict__ wp) {
    int t = blockIdx.x * 256 + threadIdx.x;
    if (t >= W_TUPLES) return;
    int lane  = t & 63;
    int ks    = (t >> 6) % 3;
    int mt_ti = t / 192;                   // ti*8+mt
    int ti    = mt_ti >> 3;
    int mt    = mt_ti & 7;
    int ch    = mt * 16 + (lane & 15);
    int kb    = ks * 32 + (lane >> 4) * 8;
    half8 h = {};
    if (kb < 72) {
        const float4* s = (const float4*)(w + (size_t)(ti * CHN + ch) * 72 + kb);
        float4 a = s[0], b = s[1];
        h[0] = (_Float16)a.x; h[1] = (_Float16)a.y;
        h[2] = (_Float16)a.z; h[3] = (_Float16)a.w;
        h[4] = (_Float16)b.x; h[5] = (_Float16)b.y;
        h[6] = (_Float16)b.z; h[7] = (_Float16)b.w;
    }
    ((half8*)wp)[t] = h;
}

// WG = 256 threads = 4 waves, 16 output px (one 16-col chunk of one row).
// Conv: per wave 2 M-tiles; 8 ti * 3 ks MFMAs (f32_16x16x32_f16), acc in regs.
// Routing: thread = (px, to), b[ti] thread-local, softmax via shfl_xor 1/2/4/8,
// squash/agreement in-lane over do via half8 LDS reads (round-4 structure).
template<bool PACKED>
__global__ __launch_bounds__(256, 3)
void caps_main(const float* __restrict__ x, const float* __restrict__ w,
               const _Float16* __restrict__ wpk,
               const float* __restrict__ cbias, const float* __restrict__ rbias,
               float* __restrict__ out)
{
    __shared__ alignas(16) float lds[LDS_F];
    _Float16* uhx = (_Float16*)lds;
    float*    xp  = lds + XP_OFF;
    float*    vbuf= lds + VB_OFF;

    const int tid  = threadIdx.x;
    const int lane = tid & 63;
    const int wv   = tid >> 6;

    // XCD-aware bijective swizzle: 1984 = 8 * 248
    const int bid  = blockIdx.x;
    const int work = (bid & 7) * 248 + (bid >> 3);
    const int n    = work / 248;
    const int rem  = work - n * 248;
    const int ho   = rem >> 2;
    const int wo0  = (rem & 3) << 4;

    // ---------------- stage x patch: 192 rows x 18 cols (fp32) ---------------
    {
        const float* xb = x + (size_t)n * 262144;
        for (int i = tid; i < XP_ROWS * 18; i += 256) {
            int row  = i / 18;
            int col  = i - row * 18;
            int tidi = row / 3;
            int kh   = row - tidi * 3;
            int gc   = wo0 + col;
            float v  = (gc < 64) ? xb[(size_t)tidi * 4096 + (ho + kh) * 64 + gc] : 0.f;
            xp[row * XP_STR + col] = v;
        }
    }
    __syncthreads();

    // ---------------- build B-fragments (f16) in LDS -------------------------
    // tuple t2 = (ti*3+ks)*64 + lane2 ; elem j = X[k = ks*32+(lane2>>4)*8+j][px = lane2&15]
    {
        for (int t2 = tid; t2 < 1536; t2 += 256) {
            int lane2 = t2 & 63;
            int ks    = (t2 >> 6) % 3;
            int ti    = t2 / 192;
            int px    = lane2 & 15;
            int kb    = ks * 32 + (lane2 >> 4) * 8;
            half8 h = {};
            #pragma unroll
            for (int j = 0; j < 8; ++j) {
                int k = kb + j;
                if (k < 72) {
                    int di = k / 9;
                    int r9 = k - di * 9;
                    int kh = r9 / 3;
                    int kw = r9 - kh * 3;
                    h[j] = (_Float16)xp[((ti * 8 + di) * 3 + kh) * XP_STR + px + kw];
                }
            }
            ((half8*)lds)[t2] = h;
        }
    }
    __syncthreads();

    // ---------------- MFMA conv: acc[ti][m] in registers ---------------------
    f32x4 acc[8][2];
    #pragma unroll
    for (int ti = 0; ti < 8; ++ti) {
        acc[ti][0] = (f32x4){0.f, 0.f, 0.f, 0.f};
        acc[ti][1] = (f32x4){0.f, 0.f, 0.f, 0.f};
    }
    {
        const half8* xf8 = (const half8*)lds;
        #pragma unroll
        for (int ti = 0; ti < 8; ++ti) {
            #pragma unroll
            for (int ks = 0; ks < 3; ++ks) {
                half8 bf = xf8[(ti * 3 + ks) * 64 + lane];
                #pragma unroll
                for (int m = 0; m < 2; ++m) {
                    const int mt = wv * 2 + m;
                    half8 af;
                    if (PACKED) {
                        af = ((const half8*)wpk)[((ti * 8 + mt) * 3 + ks) * 64 + lane];
                    } else {
                        af = (half8){};
                        int kb = ks * 32 + (lane >> 4) * 8;
                        if (kb < 72) {
                            const float4* s = (const float4*)
                                (w + (size_t)(ti * CHN + mt * 16 + (lane & 15)) * 72 + kb);
                            float4 a = s[0], b = s[1];
                            af[0] = (_Float16)a.x; af[1] = (_Float16)a.y;
                            af[2] = (_Float16)a.z; af[3] = (_Float16)a.w;
                            af[4] = (_Float16)b.x; af[5] = (_Float16)b.y;
                            af[6] = (_Float16)b.z; af[7] = (_Float16)b.w;
                        }
                    }
                    acc[ti][m] = __builtin_amdgcn_mfma_f32_16x16x32_f16(
                        af, bf, acc[ti][m], 0, 0, 0);
                }
            }
        }
    }
    __syncthreads();   // all B-fragment reads done; uhat may overwrite xf/xp

    // ---------------- epilogue: acc + cbias -> uhat (f16) in LDS -------------
    {
        const int pxe = lane & 15;
        #pragma unroll
        for (int ti = 0; ti < 8; ++ti) {
            #pragma unroll
            for (int m = 0; m < 2; ++m) {
                const int mt  = wv * 2 + m;
                const int ch0 = mt * 16 + (lane >> 4) * 4;
                float4 cb4 = *(const float4*)(cbias + ti * CHN + ch0);
                half4v hv;
                hv[0] = (_Float16)(acc[ti][m][0] + cb4.x);
                hv[1] = (_Float16)(acc[ti][m][1] + cb4.y);
                hv[2] = (_Float16)(acc[ti][m][2] + cb4.z);
                hv[3] = (_Float16)(acc[ti][m][3] + cb4.w);
                *(half4v*)(uhx + (size_t)pxe * UH_STR + ti * CHN + ch0) = hv;
            }
        }
    }
    __syncthreads();

    // ---------------- dynamic routing: thread = (px, to) ---------------------
    const int px = tid >> 4;
    const int to = tid & 15;
    const _Float16* uhp = uhx + (size_t)px * UH_STR + to * 8;

    float rb[8];
    #pragma unroll
    for (int d = 0; d < 8; ++d) rb[d] = rbias[to * 8 + d];

    float breg[8];
    #pragma unroll
    for (int t = 0; t < 8; ++t) breg[t] = 0.f;

    float v[8];

    for (int r = 0; r < 3; ++r) {
        float s[8];
        #pragma unroll
        for (int d = 0; d < 8; ++d) s[d] = rb[d];

        #pragma unroll
        for (int ti = 0; ti < 8; ++ti) {
            float c;
            if (r == 0) {
                c = 0.0625f;                    // softmax of zeros over 16
            } else {
                float bv = breg[ti];
                float m = bv;
                m = fmaxf(m, __shfl_xor(m, 1));
                m = fmaxf(m, __shfl_xor(m, 2));
                m = fmaxf(m, __shfl_xor(m, 4));
                m = fmaxf(m, __shfl_xor(m, 8));
                float e = __expf(bv - m);
                float Z = e;
                Z += __shfl_xor(Z, 1);
                Z += __shfl_xor(Z, 2);
                Z += __shfl_xor(Z, 4);
                Z += __shfl_xor(Z, 8);
                c = __fdividef(e, Z);
            }
            half8 hv = *(const half8*)(uhp + ti * CHN);
            s[0] = fmaf(c, (float)hv[0], s[0]);
            s[1] = fmaf(c, (float)hv[1], s[1]);
            s[2] = fmaf(c, (float)hv[2], s[2]);
            s[3] = fmaf(c, (float)hv[3], s[3]);
            s[4] = fmaf(c, (float)hv[4], s[4]);
            s[5] = fmaf(c, (float)hv[5], s[5]);
            s[6] = fmaf(c, (float)hv[6], s[6]);
            s[7] = fmaf(c, (float)hv[7], s[7]);
        }

        float n2 = s[0] * s[0];
        #pragma unroll
        for (int d = 1; d < 8; ++d) n2 = fmaf(s[d], s[d], n2);
        float sc = n2 / (1.f + n2) * rsqrtf(n2 + 1e-9f);
        #pragma unroll
        for (int d = 0; d < 8; ++d) v[d] = s[d] * sc;

        if (r < 2) {
            #pragma unroll
            for (int ti = 0; ti < 8; ++ti) {
                half8 hv = *(const half8*)(uhp + ti * CHN);
                float a =        v[0] * (float)hv[0];
                a = fmaf(v[1], (float)hv[1], a);
                a = fmaf(v[2], (float)hv[2], a);
                a = fmaf(v[3], (float)hv[3], a);
                a = fmaf(v[4], (float)hv[4], a);
                a = fmaf(v[5], (float)hv[5], a);
                a = fmaf(v[6], (float)hv[6], a);
                a = fmaf(v[7], (float)hv[7], a);
                breg[ti] += a;
            }
        }
    }

    // ---------------- output: transpose via vbuf then coalesced store --------
    #pragma unroll
    for (int d = 0; d < 8; ++d)
        vbuf[(to * 8 + d) * 17 + px] = v[d];
    __syncthreads();

    {
        int chh = tid >> 1;
        int jb  = (tid & 1) * 8;
        int wc0 = wo0 + jb;
        const float* vr = vbuf + chh * 17 + jb;
        size_t ob = ((size_t)(n * CHN + chh)) * 3844 + (size_t)ho * 62 + wc0;
        #pragma unroll
        for (int j = 0; j < 8; ++j)
            if (wc0 + j < 62) out[ob + j] = vr[j];
    }
}

extern "C" void kernel_launch(void* const* d_in, const int* in_sizes, int n_in,
                              void* d_out, int out_size, void* d_ws, size_t ws_size,
                              hipStream_t stream) {
    const float* x  = (const float*)d_in[0];
    const float* cw = (const float*)d_in[1];
    const float* cb = (const float*)d_in[2];
    const float* rb = (const float*)d_in[3];
    float* out = (float*)d_out;

    const int n_wg = N_ * HO * 4;   // 1984 = 8 XCDs * 248
    if (ws_size >= (size_t)WPACK_BYTES) {
        _Float16* wp = (_Float16*)d_ws;
        repack_w<<<(W_TUPLES + 255) / 256, 256, 0, stream>>>(cw, wp);
        caps_main<true><<<n_wg, 256, 0, stream>>>(x, cw, wp, cb, rb, out);
    } else {
        caps_main<false><<<n_wg, 256, 0, stream>>>(x, cw, nullptr, cb, rb, out);
    }
}

// Round 6
// 113.923 us; speedup vs baseline: 3.6121x; 1.0764x over previous
//
#include <hip/hip_runtime.h>
#include <math.h>

#define N_      8
#define HO      62
#define CHN     128
#define UH_STR  1032                 // halves per px (1024 + 8 pad)
#define XT_STR  200                  // xt col stride in halves (192 rows + pad)
#define XT_OFF_H 16512               // xt base (halves): after uhat 16*1032
#define VB_OFF_F 8256                // vbuf base (floats) = 16512 halves
#define LDS_F   10432                // total floats = 41728 B

typedef _Float16 half8  __attribute__((ext_vector_type(8)));
typedef _Float16 half4v __attribute__((ext_vector_type(4)));
typedef float    f32x4  __attribute__((ext_vector_type(4)));

#define W_TUPLES 12288               // 8 ti * 8 mt * 3 ks * 64 lanes
#define WPACK_BYTES (W_TUPLES * 16)

// ---------- DPP 16-lane-row reductions (fallback: shfl_xor) -----------------
#if defined(__has_builtin)
#if __has_builtin(__builtin_amdgcn_update_dpp)
#define HAS_DPP 1
#endif
#endif

template<int CTRL>
__device__ __forceinline__ float dppmov(float x) {
#ifdef HAS_DPP
    return __int_as_float(__builtin_amdgcn_update_dpp(
        0, __float_as_int(x), CTRL, 0xF, 0xF, true));
#else
    return 0.f;
#endif
}
__device__ __forceinline__ float rowmax16(float x) {
#ifdef HAS_DPP
    x = fmaxf(x, dppmov<0x121>(x));   // row_ror:1
    x = fmaxf(x, dppmov<0x122>(x));   // row_ror:2
    x = fmaxf(x, dppmov<0x124>(x));   // row_ror:4
    x = fmaxf(x, dppmov<0x128>(x));   // row_ror:8
#else
    x = fmaxf(x, __shfl_xor(x, 1));
    x = fmaxf(x, __shfl_xor(x, 2));
    x = fmaxf(x, __shfl_xor(x, 4));
    x = fmaxf(x, __shfl_xor(x, 8));
#endif
    return x;
}
__device__ __forceinline__ float rowsum16(float x) {
#ifdef HAS_DPP
    x += dppmov<0x121>(x);
    x += dppmov<0x122>(x);
    x += dppmov<0x124>(x);
    x += dppmov<0x128>(x);
#else
    x += __shfl_xor(x, 1);
    x += __shfl_xor(x, 2);
    x += __shfl_xor(x, 4);
    x += __shfl_xor(x, 8);
#endif
    return x;
}

// ---------- one-time weight repack with permuted K --------------------------
// kperm = ks*32 + (lane>>4)*8 + j ; physical k = 3*rem + kw where
// kw = kperm/24, rem = kperm%24 (= di*3+kh). Zero-pad kperm >= 72.
__global__ void repack_w(const float* __restrict__ w, _Float16* __restrict__ wp) {
    int t = blockIdx.x * 256 + threadIdx.x;
    if (t >= W_TUPLES) return;
    int lane = t & 63;
    int ks   = (t >> 6) % 3;
    int timt = t / 192;              // ti*8+mt
    int ti   = timt >> 3;
    int mt   = timt & 7;
    int ch   = mt * 16 + (lane & 15);
    int kb   = ks * 32 + (lane >> 4) * 8;
    const float* wr = w + (size_t)(ti * CHN + ch) * 72;
    half8 h = {};
    #pragma unroll
    for (int j = 0; j < 8; ++j) {
        int kp = kb + j;
        if (kp < 72) {
            int kw  = kp / 24;
            int rem = kp - kw * 24;
            h[j] = (_Float16)wr[rem * 3 + kw];
        }
    }
    ((half8*)wp)[t] = h;
}

// WG = 256 threads = 4 waves, 16 output px (one 16-col chunk of one row).
// Stage: x -> LDS f16 TRANSPOSED xt[col 0..19][row=ti*24+di*3+kh], so B-frags
// are direct aligned ds_read_b128 (K-permutation matches repack_w).
// Conv: per wave 2 M-tiles, 8 ti * 3 ks MFMAs (f32_16x16x32_f16).
// Routing: thread=(px,to); uhat cached in 64 f32 regs; softmax via DPP rows.
template<bool PACKED>
__global__ __launch_bounds__(256, 3)
void caps_main(const float* __restrict__ x, const float* __restrict__ w,
               const _Float16* __restrict__ wpk,
               const float* __restrict__ cbias, const float* __restrict__ rbias,
               float* __restrict__ out)
{
    __shared__ alignas(16) float lds[LDS_F];
    _Float16* uhx = (_Float16*)lds;              // 16 px * 1032 halves
    _Float16* xt  = uhx + XT_OFF_H;              // 20 cols * 200 halves
    float*    vbuf= lds + VB_OFF_F;              // aliases xt

    const int tid  = threadIdx.x;
    const int lane = tid & 63;
    const int wv   = tid >> 6;
    const int px16 = lane & 15;
    const int l4   = lane >> 4;

    // XCD-aware bijective swizzle: 1984 = 8 * 248
    const int bid  = blockIdx.x;
    const int work = (bid & 7) * 248 + (bid >> 3);
    const int n    = work / 248;
    const int rem  = work - n * 248;
    const int ho   = rem >> 2;
    const int wo0  = (rem & 3) << 4;

    // ---------------- stage x -> f16 transposed patch ------------------------
    {
        const float* xb = x + (size_t)n * 262144;
        for (int i = tid; i < 20 * 192; i += 256) {
            int row  = i / 20;                   // ti*24 + di*3 + kh
            int col  = i - row * 20;
            int tidi = row / 3;                  // ti*8+di
            int kh   = row - tidi * 3;
            int gc   = wo0 + col;
            float v  = (col < 18 && gc < 64)
                     ? xb[(size_t)tidi * 4096 + (ho + kh) * 64 + gc] : 0.f;
            xt[col * XT_STR + row] = (_Float16)v;
        }
    }
    __syncthreads();

    // ---------------- MFMA conv: acc[ti][m] in registers ---------------------
    f32x4 acc[8][2];
    #pragma unroll
    for (int ti = 0; ti < 8; ++ti) {
        acc[ti][0] = (f32x4){0.f, 0.f, 0.f, 0.f};
        acc[ti][1] = (f32x4){0.f, 0.f, 0.f, 0.f};
    }
    #pragma unroll
    for (int ks = 0; ks < 3; ++ks) {
        const int kb  = ks * 32 + l4 * 8;
        const int kw  = kb / 24;                 // 0..3 (kw==3 -> A is zero)
        const int kbm = kb - kw * 24;            // 0,8,16
        const _Float16* bbase = xt + (px16 + kw) * XT_STR + kbm;
        #pragma unroll
        for (int ti = 0; ti < 8; ++ti) {
            half8 bf = *(const half8*)(bbase + ti * 24);
            #pragma unroll
            for (int m = 0; m < 2; ++m) {
                const int mt = wv * 2 + m;
                half8 af;
                if (PACKED) {
                    af = ((const half8*)wpk)[((ti * 8 + mt) * 3 + ks) * 64 + lane];
                } else {
                    af = (half8){};
                    const float* wr = w + (size_t)(ti * CHN + mt * 16 + px16) * 72;
                    #pragma unroll
                    for (int j = 0; j < 8; ++j) {
                        int kp = kb + j;
                        if (kp < 72) {
                            int kw2  = kp / 24;
                            int rem2 = kp - kw2 * 24;
                            af[j] = (_Float16)wr[rem2 * 3 + kw2];
                        }
                    }
                }
                acc[ti][m] = __builtin_amdgcn_mfma_f32_16x16x32_f16(
                    af, bf, acc[ti][m], 0, 0, 0);
            }
        }
    }

    // ---------------- epilogue: acc + cbias -> uhat (f16) in LDS -------------
    {
        #pragma unroll
        for (int ti = 0; ti < 8; ++ti) {
            #pragma unroll
            for (int m = 0; m < 2; ++m) {
                const int mt  = wv * 2 + m;
                const int ch0 = mt * 16 + l4 * 4;
                float4 cb4 = *(const float4*)(cbias + ti * CHN + ch0);
                half4v hv;
                hv[0] = (_Float16)(acc[ti][m][0] + cb4.x);
                hv[1] = (_Float16)(acc[ti][m][1] + cb4.y);
                hv[2] = (_Float16)(acc[ti][m][2] + cb4.z);
                hv[3] = (_Float16)(acc[ti][m][3] + cb4.w);
                *(half4v*)(uhx + (size_t)px16 * UH_STR + ti * CHN + ch0) = hv;
            }
        }
    }
    __syncthreads();   // uhat complete; xt no longer needed

    // ---------------- dynamic routing: thread = (px, to) ---------------------
    const int px = tid >> 4;
    const int to = tid & 15;

    // cache uhat for this (px,to) in registers, converted once
    float uhf[64];
    {
        const _Float16* uhp = uhx + (size_t)px * UH_STR + to * 8;
        #pragma unroll
        for (int ti = 0; ti < 8; ++ti) {
            half8 hv = *(const half8*)(uhp + ti * CHN);
            #pragma unroll
            for (int d = 0; d < 8; ++d)
                uhf[ti * 8 + d] = (float)hv[d];
        }
    }

    float rb[8];
    #pragma unroll
    for (int d = 0; d < 8; ++d) rb[d] = rbias[to * 8 + d];

    float breg[8];
    #pragma unroll
    for (int t = 0; t < 8; ++t) breg[t] = 0.f;

    float v[8];

    for (int r = 0; r < 3; ++r) {
        float s[8];
        #pragma unroll
        for (int d = 0; d < 8; ++d) s[d] = rb[d];

        if (r == 0) {
            #pragma unroll
            for (int ti = 0; ti < 8; ++ti)
                #pragma unroll
                for (int d = 0; d < 8; ++d)
                    s[d] = fmaf(0.0625f, uhf[ti * 8 + d], s[d]);
        } else {
            #pragma unroll
            for (int ti = 0; ti < 8; ++ti) {
                float bv = breg[ti];
                float m  = rowmax16(bv);
                float e  = __expf(bv - m);
                float Z  = rowsum16(e);
                float c  = __fdividef(e, Z);
                #pragma unroll
                for (int d = 0; d < 8; ++d)
                    s[d] = fmaf(c, uhf[ti * 8 + d], s[d]);
            }
        }

        // squash over do (fully in-lane)
        float n2 = s[0] * s[0];
        #pragma unroll
        for (int d = 1; d < 8; ++d) n2 = fmaf(s[d], s[d], n2);
        float sc = n2 / (1.f + n2) * rsqrtf(n2 + 1e-9f);
        #pragma unroll
        for (int d = 0; d < 8; ++d) v[d] = s[d] * sc;

        if (r < 2) {
            #pragma unroll
            for (int ti = 0; ti < 8; ++ti) {
                float a = uhf[ti * 8] * v[0];
                #pragma unroll
                for (int d = 1; d < 8; ++d)
                    a = fmaf(uhf[ti * 8 + d], v[d], a);
                breg[ti] += a;
            }
        }
    }

    // ---------------- output: transpose via vbuf then coalesced store --------
    #pragma unroll
    for (int d = 0; d < 8; ++d)
        vbuf[(to * 8 + d) * 17 + px] = v[d];
    __syncthreads();

    {
        int chh = tid >> 1;
        int jb  = (tid & 1) * 8;
        int wc0 = wo0 + jb;
        const float* vr = vbuf + chh * 17 + jb;
        size_t ob = ((size_t)(n * CHN + chh)) * 3844 + (size_t)ho * 62 + wc0;
        #pragma unroll
        for (int j = 0; j < 8; ++j)
            if (wc0 + j < 62) out[ob + j] = vr[j];
    }
}

extern "C" void kernel_launch(void* const* d_in, const int* in_sizes, int n_in,
                              void* d_out, int out_size, void* d_ws, size_t ws_size,
                              hipStream_t stream) {
    const float* x  = (const float*)d_in[0];
    const float* cw = (const float*)d_in[1];
    const float* cb = (const float*)d_in[2];
    const float* rb = (const float*)d_in[3];
    float* out = (float*)d_out;

    const int n_wg = N_ * HO * 4;   // 1984 = 8 XCDs * 248
    if (ws_size >= (size_t)WPACK_BYTES) {
        _Float16* wp = (_Float16*)d_ws;
        repack_w<<<(W_TUPLES + 255) / 256, 256, 0, stream>>>(cw, wp);
        caps_main<true><<<n_wg, 256, 0, stream>>>(x, cw, wp, cb, rb, out);
    } else {
        caps_main<false><<<n_wg, 256, 0, stream>>>(x, cw, nullptr, cb, rb, out);
    }
}

// Round 7
// 104.505 us; speedup vs baseline: 3.9376x; 1.0901x over previous
//
#include <hip/hip_runtime.h>
#include <math.h>

#define N_      8
#define HO      62
#define XT_STR  200                  // halves per col (192 rows + 8 pad)
// LDS float offsets:
//   xt    : 20 cols * 200 halves = 2000 floats @ 0
//   bufS  : 2 rounds * 1024 floats             @ 2000
//   vbuf  : 128 ch * 20 floats                 @ 4048
#define BUFS_OFF 2000
#define VB_OFF   4048
#define LDS_F    6608                // 26432 B

typedef _Float16 half8 __attribute__((ext_vector_type(8)));
typedef float    f32x4 __attribute__((ext_vector_type(4)));

#define W_TUPLES 12288               // 8 ti * 8 mt * 3 ks * 64 lanes
#define WPACK_BYTES (W_TUPLES * 16)

// ---- one-time weight repack with permuted K (same layout as round 6) -------
// kperm = ks*32 + (lane>>4)*8 + j ; physical k = 3*rem + kw where
// kw = kperm/24, rem = kperm%24 (= di*3+kh). Zero-pad kperm >= 72.
__global__ void repack_w(const float* __restrict__ w, _Float16* __restrict__ wp) {
    int t = blockIdx.x * 256 + threadIdx.x;
    if (t >= W_TUPLES) return;
    int lane = t & 63;
    int ks   = (t >> 6) % 3;
    int timt = t / 192;              // ti*8+mt
    int ti   = timt >> 3;
    int mt   = timt & 7;
    int ch   = mt * 16 + (lane & 15);
    int kb   = ks * 32 + (lane >> 4) * 8;
    const float* wr = w + (size_t)(ti * 128 + ch) * 72;
    half8 h = {};
    #pragma unroll
    for (int j = 0; j < 8; ++j) {
        int kp = kb + j;
        if (kp < 72) {
            int kw  = kp / 24;
            int rem = kp - kw * 24;
            h[j] = (_Float16)wr[rem * 3 + kw];
        }
    }
    ((half8*)wp)[t] = h;
}

// WG = 512 threads = 8 waves; 16 output px (one 16-col chunk of one row).
// Wave wv owns M-tile mt=wv (16 ch). Lane: px = l&15, q = l>>4.
// Conv: 3 ks * 8 ti MFMAs (f32_16x16x32_f16); acc[ti] = uhat stays in regs.
// C-layout: ch = wv*16 + q*4 + r  ->  to = wv*2+(q>>1), do = (q&1)*4+r.
// Routing entirely in this layout: squash/agreement = in-lane + shfl_xor(16);
// softmax over to: exp-sum exchanged via 1 KB LDS buffer (no max needed:
// |b| <= ~20 so exp is fp32-safe; softmax is shift-invariant).
template<bool PACKED>
__global__ __launch_bounds__(512, 6)
void caps_main(const float* __restrict__ x, const float* __restrict__ w,
               const _Float16* __restrict__ wpk,
               const float* __restrict__ cbias, const float* __restrict__ rbias,
               float* __restrict__ out)
{
    __shared__ alignas(16) float lds[LDS_F];
    _Float16* xt  = (_Float16*)lds;
    float* bufS   = lds + BUFS_OFF;
    float* vbuf   = lds + VB_OFF;

    const int tid  = threadIdx.x;
    const int lane = tid & 63;
    const int wv   = tid >> 6;          // 0..7 = M-tile
    const int px16 = lane & 15;
    const int q    = lane >> 4;         // 0..3

    // XCD-aware bijective swizzle: 1984 = 8 * 248
    const int bid  = blockIdx.x;
    const int work = (bid & 7) * 248 + (bid >> 3);
    const int n    = work / 248;
    const int rem  = work - n * 248;
    const int ho   = rem >> 2;
    const int wo0  = (rem & 3) << 4;

    // ---------------- stage x -> f16 transposed patch xt[col][row] -----------
    {
        const float* xb = x + (size_t)n * 262144;
        for (int t = tid; t < 960; t += 512) {       // 192 rows * 5 col-quads
            int row  = t / 5;                        // (ti*8+di)*3 + kh
            int cg   = t - row * 5;
            int tidi = row / 3;
            int kh   = row - tidi * 3;
            const float* src = xb + (size_t)tidi * 4096 + (ho + kh) * 64 + wo0;
            int c0 = cg * 4;
            _Float16* dst = xt + row;
            if (c0 + 3 < 18 && wo0 + c0 + 3 < 64) {  // fully-valid vector path
                float4 v4 = *(const float4*)(src + c0);
                dst[(c0 + 0) * XT_STR] = (_Float16)v4.x;
                dst[(c0 + 1) * XT_STR] = (_Float16)v4.y;
                dst[(c0 + 2) * XT_STR] = (_Float16)v4.z;
                dst[(c0 + 3) * XT_STR] = (_Float16)v4.w;
            } else {
                #pragma unroll
                for (int j = 0; j < 4; ++j) {
                    int c = c0 + j;
                    float v = (c < 18 && wo0 + c < 64) ? src[c] : 0.f;
                    dst[c * XT_STR] = (_Float16)v;
                }
            }
        }
    }
    __syncthreads();

    // ---------------- MFMA conv: acc[ti] = uhat in registers -----------------
    f32x4 acc[8];
    #pragma unroll
    for (int ti = 0; ti < 8; ++ti) acc[ti] = (f32x4){0.f, 0.f, 0.f, 0.f};

    #pragma unroll
    for (int ks = 0; ks < 3; ++ks) {
        const int kb  = ks * 32 + q * 8;
        const int kw  = kb / 24;                 // 0..3 (kw==3 -> A is zero)
        const int kbm = kb - kw * 24;
        const _Float16* bbase = xt + (px16 + kw) * XT_STR + kbm;
        #pragma unroll
        for (int ti = 0; ti < 8; ++ti) {
            half8 bf = *(const half8*)(bbase + ti * 24);
            half8 af;
            if (PACKED) {
                af = ((const half8*)wpk)[((ti * 8 + wv) * 3 + ks) * 64 + lane];
            } else {
                af = (half8){};
                const float* wr = w + (size_t)(ti * 128 + wv * 16 + px16) * 72;
                #pragma unroll
                for (int j = 0; j < 8; ++j) {
                    int kp = kb + j;
                    if (kp < 72) {
                        int kw2 = kp / 24, rem2 = kp - kw2 * 24;
                        af[j] = (_Float16)wr[rem2 * 3 + kw2];
                    }
                }
            }
            acc[ti] = __builtin_amdgcn_mfma_f32_16x16x32_f16(af, bf, acc[ti], 0, 0, 0);
        }
    }

    // fold conv bias (ch = wv*16 + q*4 + r)
    #pragma unroll
    for (int ti = 0; ti < 8; ++ti) {
        float4 cb4 = *(const float4*)(cbias + ti * 128 + wv * 16 + q * 4);
        acc[ti][0] += cb4.x; acc[ti][1] += cb4.y;
        acc[ti][2] += cb4.z; acc[ti][3] += cb4.w;
    }
    const float4 rb4 = *(const float4*)(rbias + wv * 16 + q * 4);

    // ---------------- dynamic routing in conv layout -------------------------
    float breg[8];
    #pragma unroll
    for (int t = 0; t < 8; ++t) breg[t] = 0.f;

    f32x4 v = {0.f, 0.f, 0.f, 0.f};

    #pragma unroll
    for (int r = 0; r < 3; ++r) {
        f32x4 s = {rb4.x, rb4.y, rb4.z, rb4.w};

        if (r == 0) {
            // b == 0 -> c = 1/16 exactly
            #pragma unroll
            for (int ti = 0; ti < 8; ++ti) {
                s[0] = fmaf(0.0625f, acc[ti][0], s[0]);
                s[1] = fmaf(0.0625f, acc[ti][1], s[1]);
                s[2] = fmaf(0.0625f, acc[ti][2], s[2]);
                s[3] = fmaf(0.0625f, acc[ti][3], s[3]);
            }
        } else {
            float* bufX = bufS + (r - 1) * 1024;   // [ti][px][wv]
            // wave partial: sum of exp over this wave's two to's
            #pragma unroll
            for (int ti = 0; ti < 8; ++ti) {
                float e  = __expf(breg[ti]);
                float Sw = e + __shfl_xor(e, 32);
                if (q == 0) bufX[ti * 128 + px16 * 8 + wv] = Sw;
            }
            __syncthreads();
            #pragma unroll
            for (int ti = 0; ti < 8; ++ti) {
                f32x4 za = *(const f32x4*)(bufX + ti * 128 + px16 * 8);
                f32x4 zb = *(const f32x4*)(bufX + ti * 128 + px16 * 8 + 4);
                float Z = ((za[0] + za[1]) + (za[2] + za[3]))
                        + ((zb[0] + zb[1]) + (zb[2] + zb[3]));
                float c = __fdividef(__expf(breg[ti]), Z);
                s[0] = fmaf(c, acc[ti][0], s[0]);
                s[1] = fmaf(c, acc[ti][1], s[1]);
                s[2] = fmaf(c, acc[ti][2], s[2]);
                s[3] = fmaf(c, acc[ti][3], s[3]);
            }
        }

        // squash over do: in-lane (r) + shfl_xor(16) (q&1)
        float n2 = s[0] * s[0] + s[1] * s[1] + s[2] * s[2] + s[3] * s[3];
        n2 += __shfl_xor(n2, 16);
        float sc = n2 / (1.f + n2) * rsqrtf(n2 + 1e-9f);
        v[0] = s[0] * sc; v[1] = s[1] * sc; v[2] = s[2] * sc; v[3] = s[3] * sc;

        if (r < 2) {
            // agreement: b[ti][to] += sum_do uh*v
            #pragma unroll
            for (int ti = 0; ti < 8; ++ti) {
                float a = acc[ti][0] * v[0] + acc[ti][1] * v[1]
                        + acc[ti][2] * v[2] + acc[ti][3] * v[3];
                a += __shfl_xor(a, 16);
                breg[ti] += a;
            }
        }
    }

    // ---------------- output: transpose via vbuf then coalesced store --------
    {
        const int chb = wv * 16 + q * 4;
        vbuf[(chb + 0) * 20 + px16] = v[0];
        vbuf[(chb + 1) * 20 + px16] = v[1];
        vbuf[(chb + 2) * 20 + px16] = v[2];
        vbuf[(chb + 3) * 20 + px16] = v[3];
    }
    __syncthreads();
    {
        int ch  = tid >> 2;
        int jb  = (tid & 3) * 4;
        int wc0 = wo0 + jb;
        float4 vv = *(const float4*)(vbuf + ch * 20 + jb);
        size_t ob = ((size_t)(n * 128 + ch)) * 3844 + (size_t)ho * 62 + wc0;
        if (wc0 + 3 < 62) {
            out[ob + 0] = vv.x; out[ob + 1] = vv.y;
            out[ob + 2] = vv.z; out[ob + 3] = vv.w;
        } else {
            if (wc0 + 0 < 62) out[ob + 0] = vv.x;
            if (wc0 + 1 < 62) out[ob + 1] = vv.y;
            if (wc0 + 2 < 62) out[ob + 2] = vv.z;
            if (wc0 + 3 < 62) out[ob + 3] = vv.w;
        }
    }
}

extern "C" void kernel_launch(void* const* d_in, const int* in_sizes, int n_in,
                              void* d_out, int out_size, void* d_ws, size_t ws_size,
                              hipStream_t stream) {
    const float* x  = (const float*)d_in[0];
    const float* cw = (const float*)d_in[1];
    const float* cb = (const float*)d_in[2];
    const float* rb = (const float*)d_in[3];
    float* out = (float*)d_out;

    const int n_wg = N_ * HO * 4;   // 1984 = 8 XCDs * 248
    if (ws_size >= (size_t)WPACK_BYTES) {
        _Float16* wp = (_Float16*)d_ws;
        repack_w<<<(W_TUPLES + 255) / 256, 256, 0, stream>>>(cw, wp);
        caps_main<true><<<n_wg, 512, 0, stream>>>(x, cw, wp, cb, rb, out);
    } else {
        caps_main<false><<<n_wg, 512, 0, stream>>>(x, cw, nullptr, cb, rb, out);
    }
}

// Round 8
// 102.145 us; speedup vs baseline: 4.0286x; 1.0231x over previous
//
#include <hip/hip_runtime.h>
#include <math.h>

#define N_      8
#define HO      62
#define XT_STR  200                  // halves per col (192 rows + 8 pad)
// LDS float offsets:
//   xt   : 20 cols * 200 halves = 2000 floats @ 0
//   bufS : 2 rounds * 1536 floats ([ti][px*12+wv])  @ 2000
//   vbuf : 128 ch * 20 floats                        @ 5072
#define BUFS_OFF 2000
#define VB_OFF   5072
#define LDS_F    7632                // 30528 B

typedef _Float16 half8  __attribute__((ext_vector_type(8)));
typedef _Float16 half4v __attribute__((ext_vector_type(4)));
typedef _Float16 half2v __attribute__((ext_vector_type(2)));
typedef float    f32x4  __attribute__((ext_vector_type(4)));

#define W_TUPLES 12288               // 8 ti * 8 mt * 3 ks * 64 lanes
#define W_PAIRS  (W_TUPLES * 4)      // 49152 half2 outputs
#define WPACK_BYTES (W_TUPLES * 16)

// ---- one-time weight repack with permuted K, element-pair parallel ---------
// out half index = (((ti*8+mt)*3+ks)*64 + lane)*8 + j ; kperm = ks*32+q*8+j;
// physical k = rem*3 + kw with kw = kperm/24, rem = kperm%24. Zero for kperm>=72.
__global__ __launch_bounds__(256)
void repack_w(const float* __restrict__ w, _Float16* __restrict__ wp) {
    int o = blockIdx.x * 256 + threadIdx.x;        // one half2 per thread
    if (o >= W_PAIRS) return;
    int j2   = (o & 3) * 2;
    int lane = (o >> 2) & 63;
    int g3   = o >> 8;                             // timt*3 + ks
    int ks   = g3 % 3;
    int timt = g3 / 3;                             // ti*8 + mt
    int q    = lane >> 4;
    int cl   = lane & 15;
    int ti   = timt >> 3;
    int mt   = timt & 7;
    const float* wr = w + (size_t)(ti * 128 + mt * 16 + cl) * 72;
    int kp = ks * 32 + q * 8 + j2;
    float v0 = 0.f, v1 = 0.f;
    if (kp < 72)     { int kw = kp / 24;        int rm = kp - kw * 24;       v0 = wr[rm * 3 + kw]; }
    if (kp + 1 < 72) { int kw = (kp + 1) / 24;  int rm = (kp + 1) - kw * 24; v1 = wr[rm * 3 + kw]; }
    half2v h = { (_Float16)v0, (_Float16)v1 };
    ((half2v*)wp)[o] = h;
}

// WG = 512 threads = 8 waves; 16 output px (one 16-col chunk of one row).
// Wave wv owns M-tile mt=wv (16 ch). Lane: px = l&15, q = l>>4.
// Conv: 3 ks * 8 ti MFMAs (f32_16x16x32_f16); acc[ti] = uhat stays in regs.
// C-layout: ch = wv*16 + q*4 + r  ->  to = wv*2+(q>>1), do = (q&1)*4+r.
// Routing in this layout: squash/agreement = in-lane + shfl_xor(16);
// softmax over to: exp-sums via bufX [ti][px*12+wv] (bank-conflict-free).
template<bool PACKED>
__global__ __launch_bounds__(512, 6)
void caps_main(const float* __restrict__ x, const float* __restrict__ w,
               const _Float16* __restrict__ wpk,
               const float* __restrict__ cbias, const float* __restrict__ rbias,
               float* __restrict__ out)
{
    __shared__ alignas(16) float lds[LDS_F];
    _Float16* xt  = (_Float16*)lds;
    float* bufS   = lds + BUFS_OFF;
    float* vbuf   = lds + VB_OFF;

    const int tid  = threadIdx.x;
    const int lane = tid & 63;
    const int wv   = tid >> 6;          // 0..7 = M-tile
    const int px16 = lane & 15;
    const int q    = lane >> 4;         // 0..3

    // XCD-aware bijective swizzle: 1984 = 8 * 248
    const int bid  = blockIdx.x;
    const int work = (bid & 7) * 248 + (bid >> 3);
    const int n    = work / 248;
    const int rem  = work - n * 248;
    const int ho   = rem >> 2;
    const int wo0  = (rem & 3) << 4;

    // ---- stage x -> f16 transposed patch xt[col][row], row-quad b64 writes --
    {
        const float* xb = x + (size_t)n * 262144;
        for (int t = tid; t < 960; t += 512) {     // 48 row-quads * 20 cols
            int rq  = t / 20;
            int col = t - rq * 20;
            bool valid = (col < 18) && (wo0 + col < 64);
            half4v d;
            #pragma unroll
            for (int rr = 0; rr < 4; ++rr) {
                int row  = rq * 4 + rr;            // (ti*8+di)*3 + kh
                int tidi = row / 3;
                int kh   = row - tidi * 3;
                float v  = valid
                         ? xb[(size_t)tidi * 4096 + (ho + kh) * 64 + wo0 + col]
                         : 0.f;
                d[rr] = (_Float16)v;
            }
            *(half4v*)(xt + col * XT_STR + rq * 4) = d;
        }
    }
    __syncthreads();

    // ---------------- MFMA conv: acc[ti] = uhat in registers -----------------
    f32x4 acc[8];
    #pragma unroll
    for (int ti = 0; ti < 8; ++ti) acc[ti] = (f32x4){0.f, 0.f, 0.f, 0.f};

    #pragma unroll
    for (int ks = 0; ks < 3; ++ks) {
        const int kb  = ks * 32 + q * 8;
        const int kw  = kb / 24;                 // 0..3 (kw==3 -> both sides zero)
        const int kbm = kb - kw * 24;
        const _Float16* bbase = xt + (px16 + kw) * XT_STR + kbm;
        #pragma unroll
        for (int ti = 0; ti < 8; ++ti) {
            half8 bf = *(const half8*)(bbase + ti * 24);
            half8 af;
            if (PACKED) {
                af = ((const half8*)wpk)[((ti * 8 + wv) * 3 + ks) * 64 + lane];
            } else {
                af = (half8){};
                const float* wr = w + (size_t)(ti * 128 + wv * 16 + px16) * 72;
                #pragma unroll
                for (int j = 0; j < 8; ++j) {
                    int kp = kb + j;
                    if (kp < 72) {
                        int kw2 = kp / 24, rem2 = kp - kw2 * 24;
                        af[j] = (_Float16)wr[rem2 * 3 + kw2];
                    }
                }
            }
            acc[ti] = __builtin_amdgcn_mfma_f32_16x16x32_f16(af, bf, acc[ti], 0, 0, 0);
        }
    }

    // fold conv bias (ch = wv*16 + q*4 + r)
    #pragma unroll
    for (int ti = 0; ti < 8; ++ti) {
        float4 cb4 = *(const float4*)(cbias + ti * 128 + wv * 16 + q * 4);
        acc[ti][0] += cb4.x; acc[ti][1] += cb4.y;
        acc[ti][2] += cb4.z; acc[ti][3] += cb4.w;
    }
    const float4 rb4 = *(const float4*)(rbias + wv * 16 + q * 4);

    // ---------------- dynamic routing in conv layout -------------------------
    float breg[8];
    #pragma unroll
    for (int t = 0; t < 8; ++t) breg[t] = 0.f;

    f32x4 v = {0.f, 0.f, 0.f, 0.f};

    #pragma unroll
    for (int r = 0; r < 3; ++r) {
        f32x4 s = {rb4.x, rb4.y, rb4.z, rb4.w};

        if (r == 0) {
            // b == 0 -> c = 1/16 exactly
            #pragma unroll
            for (int ti = 0; ti < 8; ++ti) {
                s[0] = fmaf(0.0625f, acc[ti][0], s[0]);
                s[1] = fmaf(0.0625f, acc[ti][1], s[1]);
                s[2] = fmaf(0.0625f, acc[ti][2], s[2]);
                s[3] = fmaf(0.0625f, acc[ti][3], s[3]);
            }
        } else {
            float* bufX = bufS + (r - 1) * 1536;   // [ti][px*12 + wv]
            float e[8];
            #pragma unroll
            for (int ti = 0; ti < 8; ++ti) {
                e[ti] = __expf(breg[ti]);
                float Sw = e[ti] + __shfl_xor(e[ti], 32);   // both to's of wave
                if (q == 0) bufX[ti * 192 + px16 * 12 + wv] = Sw;
            }
            __syncthreads();
            #pragma unroll
            for (int ti = 0; ti < 8; ++ti) {
                f32x4 za = *(const f32x4*)(bufX + ti * 192 + px16 * 12);
                f32x4 zb = *(const f32x4*)(bufX + ti * 192 + px16 * 12 + 4);
                float Z = ((za[0] + za[1]) + (za[2] + za[3]))
                        + ((zb[0] + zb[1]) + (zb[2] + zb[3]));
                float c = __fdividef(e[ti], Z);
                s[0] = fmaf(c, acc[ti][0], s[0]);
                s[1] = fmaf(c, acc[ti][1], s[1]);
                s[2] = fmaf(c, acc[ti][2], s[2]);
                s[3] = fmaf(c, acc[ti][3], s[3]);
            }
        }

        // squash over do: in-lane (r) + shfl_xor(16) (q&1)
        float n2 = s[0] * s[0] + s[1] * s[1] + s[2] * s[2] + s[3] * s[3];
        n2 += __shfl_xor(n2, 16);
        float sc = n2 / (1.f + n2) * rsqrtf(n2 + 1e-9f);
        v[0] = s[0] * sc; v[1] = s[1] * sc; v[2] = s[2] * sc; v[3] = s[3] * sc;

        if (r < 2) {
            // agreement: b[ti][to] += sum_do uh*v
            #pragma unroll
            for (int ti = 0; ti < 8; ++ti) {
                float a = acc[ti][0] * v[0] + acc[ti][1] * v[1]
                        + acc[ti][2] * v[2] + acc[ti][3] * v[3];
                a += __shfl_xor(a, 16);
                breg[ti] += a;
            }
        }
    }

    // ---------------- output: transpose via vbuf then coalesced store --------
    {
        const int chb = wv * 16 + q * 4;
        vbuf[(chb + 0) * 20 + px16] = v[0];
        vbuf[(chb + 1) * 20 + px16] = v[1];
        vbuf[(chb + 2) * 20 + px16] = v[2];
        vbuf[(chb + 3) * 20 + px16] = v[3];
    }
    __syncthreads();
    {
        int ch  = tid >> 2;
        int jb  = (tid & 3) * 4;
        int wc0 = wo0 + jb;
        float4 vv = *(const float4*)(vbuf + ch * 20 + jb);
        size_t ob = ((size_t)(n * 128 + ch)) * 3844 + (size_t)ho * 62 + wc0;
        if (wc0 + 3 < 62) {
            out[ob + 0] = vv.x; out[ob + 1] = vv.y;
            out[ob + 2] = vv.z; out[ob + 3] = vv.w;
        } else {
            if (wc0 + 0 < 62) out[ob + 0] = vv.x;
            if (wc0 + 1 < 62) out[ob + 1] = vv.y;
            if (wc0 + 2 < 62) out[ob + 2] = vv.z;
            if (wc0 + 3 < 62) out[ob + 3] = vv.w;
        }
    }
}

extern "C" void kernel_launch(void* const* d_in, const int* in_sizes, int n_in,
                              void* d_out, int out_size, void* d_ws, size_t ws_size,
                              hipStream_t stream) {
    const float* x  = (const float*)d_in[0];
    const float* cw = (const float*)d_in[1];
    const float* cb = (const float*)d_in[2];
    const float* rb = (const float*)d_in[3];
    float* out = (float*)d_out;

    const int n_wg = N_ * HO * 4;   // 1984 = 8 XCDs * 248
    if (ws_size >= (size_t)WPACK_BYTES) {
        _Float16* wp = (_Float16*)d_ws;
        repack_w<<<(W_PAIRS + 255) / 256, 256, 0, stream>>>(cw, wp);
        caps_main<true><<<n_wg, 512, 0, stream>>>(x, cw, wp, cb, rb, out);
    } else {
        caps_main<false><<<n_wg, 512, 0, stream>>>(x, cw, nullptr, cb, rb, out);
    }
}